// Round 5
// baseline (249.205 us; speedup 1.0000x reference)
//
#include <hip/hip_runtime.h>
#include <math.h>

#define C    128
#define C4   32
#define NN   2304          // 48*48
#define BN_EPS 1e-5f
#define NEG_INF -3.402823466e38f
#define LOG2E 1.4426950408889634f

typedef short bf16x8 __attribute__((ext_vector_type(8)));
typedef float f32x4 __attribute__((ext_vector_type(4)));

// barrier that only drains LDS (lgkmcnt) — leaves prefetched global loads in flight.
// Safe when the barrier only orders LDS traffic (__syncthreads would drain vmcnt(0)).
#define SOFT_BARRIER() asm volatile("s_waitcnt lgkmcnt(0)\n\ts_barrier" ::: "memory")

__device__ inline unsigned short f2bf(float f) {
    unsigned int u = __float_as_uint(f);
    u += 0x7fffu + ((u >> 16) & 1u);
    return (unsigned short)(u >> 16);
}

// pack two fp32 -> packed bf16 pair (low = a, high = b), RNE
__device__ inline unsigned int pk2bf(float a, float b) {
#if __has_builtin(__builtin_amdgcn_cvt_pk_bf16_f32)
    typedef __bf16 bf2 __attribute__((ext_vector_type(2)));
    bf2 v = __builtin_amdgcn_cvt_pk_bf16_f32(a, b);
    return __builtin_bit_cast(unsigned int, v);
#else
    unsigned int ua = __float_as_uint(a); ua += 0x7fffu + ((ua >> 16) & 1u);
    unsigned int ub = __float_as_uint(b); ub += 0x7fffu + ((ub >> 16) & 1u);
    return __builtin_amdgcn_perm(ub, ua, 0x07060302u);
#endif
}

__device__ inline float fexp2(float x) {
#if __has_builtin(__builtin_amdgcn_exp2f)
    return __builtin_amdgcn_exp2f(x);
#else
    return __expf(x * 0.69314718055994531f);
#endif
}

// ---------------- workspace layout ----------------
// ushort region:
//   Kt  [16][2304][32]  @0         (1179648)   NOTE: K pre-scaled by log2(e)
//   Qt  [16][2304][32]  @1179648   (1179648)
//   Vf  [16][128][2304] @2359296   (4718592)
//   wkq_bf [32][128]    @7077888   (4096)
//   wv_bf  [128][128]   @7081984   (16384)
//   wred_bf[128][256]   @7098368   (32768)
// float region:
//   bmax[16*324], bsum[16*324], Ms[16], Sinv[16], kq_sh[32], v_sh[128], red_sh[128]

__global__ __launch_bounds__(256) void k_wprep(
    const float* __restrict__ wkq, const float* __restrict__ kq_g,
    const float* __restrict__ kq_b, const float* __restrict__ kq_m,
    const float* __restrict__ kq_v,
    const float* __restrict__ wv, const float* __restrict__ v_g,
    const float* __restrict__ v_b, const float* __restrict__ v_m,
    const float* __restrict__ v_v,
    const float* __restrict__ wred, const float* __restrict__ red_g,
    const float* __restrict__ red_b, const float* __restrict__ red_m,
    const float* __restrict__ red_v,
    unsigned short* __restrict__ wkq_bf, unsigned short* __restrict__ wv_bf,
    unsigned short* __restrict__ wred_bf,
    float* __restrict__ kq_sh, float* __restrict__ v_sh, float* __restrict__ red_sh)
{
    const int t = blockIdx.x * 256 + threadIdx.x;
    if (t < 4096) {
        const int o = t >> 7;
        const float sc = kq_g[o] * rsqrtf(kq_v[o] + BN_EPS);
        wkq_bf[t] = f2bf(wkq[t] * sc);
        if ((t & 127) == 0) kq_sh[o] = kq_b[o] - kq_m[o] * sc;
    } else if (t < 4096 + 16384) {
        const int e = t - 4096;
        const int o = e >> 7;
        const float sc = v_g[o] * rsqrtf(v_v[o] + BN_EPS);
        wv_bf[e] = f2bf(wv[e] * sc);
        if ((e & 127) == 0) v_sh[o] = v_b[o] - v_m[o] * sc;
    } else if (t < 4096 + 16384 + 32768) {
        const int e = t - 20480;
        const int o = e >> 8;
        const float sc = red_g[o] * rsqrtf(red_v[o] + BN_EPS);
        wred_bf[e] = f2bf(wred[e] * sc);
        if ((e & 255) == 0) red_sh[o] = red_b[o] - red_m[o] * sc;
    }
}

// ---- K/Q conv via MFMA: bf16 transposed out [b][n][32o]; K (z==0) scaled by log2(e)
// Pipelined: double-buffered Xs, loads for chunk k+1 issued during chunk k,
// ONE soft barrier per chunk (between LDS write and MFMA read).
__global__ __launch_bounds__(256) void k_kq(
    const float* __restrict__ x0, const float* __restrict__ x1,
    const unsigned short* __restrict__ wbf, const float* __restrict__ shift,
    unsigned short* __restrict__ Kt, unsigned short* __restrict__ Qt)
{
    constexpr int NTILE = 128, R = 8;
    __shared__ unsigned short Xs[2][NTILE][40];

    const int tid = threadIdx.x;
    const int w = tid >> 6, lane = tid & 63;
    const int quad = lane >> 4, l16 = lane & 15;
    const int b = blockIdx.y, n0 = blockIdx.x * NTILE;
    const int nbase = w * 32;

    const float* xin = (blockIdx.z ? x1 : x0) + (size_t)b * C * NN;
    const int p = tid & 15, g = tid >> 4;

    f32x4 acc[2][2];
#pragma unroll
    for (int mt = 0; mt < 2; mt++)
#pragma unroll
        for (int nt = 0; nt < 2; nt++) acc[mt][nt] = (f32x4){0.f, 0.f, 0.f, 0.f};

    const float* xrb = xin + n0 + g * R;
    float av[R], bv[R];
    {
        const float* xr = xrb + (size_t)(2 * p) * NN;
#pragma unroll
        for (int i4 = 0; i4 < R; i4 += 4) {
            *(float4*)&av[i4] = *(const float4*)&xr[i4];
            *(float4*)&bv[i4] = *(const float4*)&xr[NN + i4];
        }
    }

    for (int k = 0; k < 4; ++k) {
        unsigned int uu[R];
#pragma unroll
        for (int i = 0; i < R; i++) uu[i] = pk2bf(av[i], bv[i]);
        if (k < 3) {
            const float* xr = xrb + (size_t)((k + 1) * 32 + 2 * p) * NN;
#pragma unroll
            for (int i4 = 0; i4 < R; i4 += 4) {
                *(float4*)&av[i4] = *(const float4*)&xr[i4];
                *(float4*)&bv[i4] = *(const float4*)&xr[NN + i4];
            }
        }
        unsigned int* Xw = (unsigned int*)Xs[k & 1];
#pragma unroll
        for (int i = 0; i < R; i++)
            Xw[(g * R + i) * 20 + p] = uu[i];
        SOFT_BARRIER();
        bf16x8 af[2];
#pragma unroll
        for (int mt = 0; mt < 2; mt++)
            af[mt] = *(const bf16x8*)&wbf[(size_t)(mt * 16 + l16) * C + k * 32 + quad * 8];
#pragma unroll
        for (int nt = 0; nt < 2; nt++) {
            const bf16x8 bfr = *(const bf16x8*)&Xs[k & 1][nbase + nt * 16 + l16][quad * 8];
#pragma unroll
            for (int mt = 0; mt < 2; mt++)
                acc[mt][nt] = __builtin_amdgcn_mfma_f32_16x16x32_bf16(af[mt], bfr, acc[mt][nt], 0, 0, 0);
        }
    }

    unsigned short* ob16 = blockIdx.z ? Qt : Kt;
    const float osc = blockIdx.z ? 1.f : LOG2E;
#pragma unroll
    for (int mt = 0; mt < 2; mt++)
#pragma unroll
        for (int nt = 0; nt < 2; nt++)
#pragma unroll
            for (int r = 0; r < 4; r++) {
                const int o = mt * 16 + quad * 4 + r;
                const int n = n0 + nbase + nt * 16 + l16;
                const float sh = shift[o];
                ob16[((size_t)b * NN + n) * 32 + o] =
                    f2bf(fmaxf(acc[mt][nt][r] + sh, 0.f) * osc);
            }
}

// ---- fused reduce-conv + V-conv ----
// red: x[o][n] = relu(bn(wred * xcat)) -> fp32 d_out ch 0..127 AND bf16 LDS tile
// v:   V[o][n] = relu(bn(wv * x))      -> bf16 Vf  (x consumed from LDS, no global round-trip)
// red phase pipelined: double-buffered Xs, ONE soft barrier per c-chunk.
__global__ __launch_bounds__(256) void k_redv(
    const float* __restrict__ xcat,
    const unsigned short* __restrict__ wred_bf, const float* __restrict__ red_sh,
    const unsigned short* __restrict__ wv_bf,  const float* __restrict__ v_sh,
    float* __restrict__ out, unsigned short* __restrict__ Vf)
{
    __shared__ unsigned short Xs[2][48][40];  // double-buffered staging (48 n-rows)
    __shared__ unsigned int   Xv[64 * 49];    // x as bf16-pairs: [cp][n], stride 49 dwords

    const int tid = threadIdx.x;
    const int w = tid >> 6, lane = tid & 63;
    const int quad = lane >> 4, l16 = lane & 15;
    const int b = blockIdx.y, n0 = blockIdx.x * 48;
    const float* xin = xcat + (size_t)b * 2 * C * NN;
    const int p = tid & 15, g = tid >> 4;

    f32x4 acc[2][3];
#pragma unroll
    for (int mt = 0; mt < 2; mt++)
#pragma unroll
        for (int nt = 0; nt < 3; nt++) acc[mt][nt] = (f32x4){0.f, 0.f, 0.f, 0.f};

    float4 av, bv;
    if (g < 12) {
        const float* xr = xin + (size_t)(2 * p) * NN + n0 + g * 4;
        av = *(const float4*)&xr[0];
        bv = *(const float4*)&xr[NN];
    }

    // ---- red phase: 256-c sweep, pipelined ----
    for (int k = 0; k < 8; ++k) {
        if (g < 12) {   // 192 threads stage 48 rows x 16 c-pairs
            const unsigned int u0 = pk2bf(av.x, bv.x);
            const unsigned int u1 = pk2bf(av.y, bv.y);
            const unsigned int u2 = pk2bf(av.z, bv.z);
            const unsigned int u3 = pk2bf(av.w, bv.w);
            if (k < 7) {
                const float* xr = xin + (size_t)((k + 1) * 32 + 2 * p) * NN + n0 + g * 4;
                av = *(const float4*)&xr[0];
                bv = *(const float4*)&xr[NN];
            }
            unsigned int* Xw = (unsigned int*)Xs[k & 1];
            Xw[(g * 4 + 0) * 20 + p] = u0;
            Xw[(g * 4 + 1) * 20 + p] = u1;
            Xw[(g * 4 + 2) * 20 + p] = u2;
            Xw[(g * 4 + 3) * 20 + p] = u3;
        }
        SOFT_BARRIER();
        bf16x8 af[2];
#pragma unroll
        for (int mt = 0; mt < 2; mt++)
            af[mt] = *(const bf16x8*)&wred_bf[(size_t)(w * 32 + mt * 16 + l16) * (2 * C) + k * 32 + quad * 8];
#pragma unroll
        for (int nt = 0; nt < 3; nt++) {
            const bf16x8 bfr = *(const bf16x8*)&Xs[k & 1][nt * 16 + l16][quad * 8];
#pragma unroll
            for (int mt = 0; mt < 2; mt++)
                acc[mt][nt] = __builtin_amdgcn_mfma_f32_16x16x32_bf16(af[mt], bfr, acc[mt][nt], 0, 0, 0);
        }
    }

    // red epilogue: fp32 -> d_out, bf16 pairs -> Xv[cp][n]
    {
        float* ob = out + (size_t)b * (2 * C * NN);
#pragma unroll
        for (int mt = 0; mt < 2; mt++) {
            float sh[4];
#pragma unroll
            for (int r = 0; r < 4; r++) sh[r] = red_sh[w * 32 + mt * 16 + quad * 4 + r];
#pragma unroll
            for (int nt = 0; nt < 3; nt++) {
                const int n = n0 + nt * 16 + l16;
                float v[4];
#pragma unroll
                for (int r = 0; r < 4; r++) {
                    const int o = w * 32 + mt * 16 + quad * 4 + r;
                    v[r] = fmaxf(acc[mt][nt][r] + sh[r], 0.f);
                    ob[(size_t)o * NN + n] = v[r];
                }
                const int op0 = 16 * w + mt * 8 + quad * 2;   // c-pair row
                Xv[(op0 + 0) * 49 + nt * 16 + l16] = pk2bf(v[0], v[1]);
                Xv[(op0 + 1) * 49 + nt * 16 + l16] = pk2bf(v[2], v[3]);
            }
        }
    }
    SOFT_BARRIER();   // order Xv LDS traffic only; fp32 out-stores stay in flight

    // ---- V phase: 128-c sweep reading x from Xv ----
    f32x4 vacc[2][3];
#pragma unroll
    for (int mt = 0; mt < 2; mt++)
#pragma unroll
        for (int nt = 0; nt < 3; nt++) vacc[mt][nt] = (f32x4){0.f, 0.f, 0.f, 0.f};

    for (int c0 = 0; c0 < C; c0 += 32) {
        bf16x8 af[2];
#pragma unroll
        for (int mt = 0; mt < 2; mt++)
            af[mt] = *(const bf16x8*)&wv_bf[(size_t)(w * 32 + mt * 16 + l16) * C + c0 + quad * 8];
#pragma unroll
        for (int nt = 0; nt < 3; nt++) {
            const int col = nt * 16 + l16;
            const int cp0 = c0 / 2 + quad * 4;
            uint4 u;
            u.x = Xv[(cp0 + 0) * 49 + col];
            u.y = Xv[(cp0 + 1) * 49 + col];
            u.z = Xv[(cp0 + 2) * 49 + col];
            u.w = Xv[(cp0 + 3) * 49 + col];
            const bf16x8 bfr = __builtin_bit_cast(bf16x8, u);
#pragma unroll
            for (int mt = 0; mt < 2; mt++)
                vacc[mt][nt] = __builtin_amdgcn_mfma_f32_16x16x32_bf16(af[mt], bfr, vacc[mt][nt], 0, 0, 0);
        }
    }

#pragma unroll
    for (int mt = 0; mt < 2; mt++) {
        float sh[4];
#pragma unroll
        for (int r = 0; r < 4; r++) sh[r] = v_sh[w * 32 + mt * 16 + quad * 4 + r];
#pragma unroll
        for (int nt = 0; nt < 3; nt++)
#pragma unroll
            for (int r = 0; r < 4; r++) {
                const int o = w * 32 + mt * 16 + quad * 4 + r;
                const int n = n0 + nt * 16 + l16;
                Vf[((size_t)b * C + o) * NN + n] = f2bf(fmaxf(vacc[mt][nt][r] + sh[r], 0.f));
            }
    }
}

// stats: 128(m) x 128(n) scaled-KQ tile; all 16 MFMAs first, then bulk reduce.
// XCD-aware flat grid (5184 = 648*8): xcd = wg%8 owns batches {2*xcd, 2*xcd+1},
// so per-XCD L2 working set = Kt+Qt of 2 batches (~1.2 MB) instead of all 16 (4.7 MB).
__global__ __launch_bounds__(256) void k_stats(
    const unsigned short* __restrict__ Kt, const unsigned short* __restrict__ Qt,
    float* __restrict__ bmax, float* __restrict__ bsum)
{
    const int tid = threadIdx.x;
    const int w = tid >> 6, lane = tid & 63;
    const int quad = lane >> 4, l16 = lane & 15;
    const int wg = blockIdx.x;
    const int xcd = wg & 7;
    const int slot = wg >> 3;                 // 0..647
    const int b = xcd * 2 + slot / 324;
    const int tile = slot % 324;
    const int my = tile / 18, mx = tile % 18;
    const int n0 = mx * 128, m0 = my * 128;
    const unsigned short* Kb = Kt + (size_t)b * NN * 32;
    const unsigned short* Qb = Qt + (size_t)b * NN * 32;

    bf16x8 kf[8], qf[2];
#pragma unroll
    for (int nt = 0; nt < 8; nt++)
        kf[nt] = *(const bf16x8*)&Kb[(size_t)(n0 + nt * 16 + l16) * 32 + quad * 8];
#pragma unroll
    for (int mt = 0; mt < 2; mt++)
        qf[mt] = *(const bf16x8*)&Qb[(size_t)(m0 + w * 32 + mt * 16 + l16) * 32 + quad * 8];

    f32x4 s[16];
#pragma unroll
    for (int mt = 0; mt < 2; mt++)
#pragma unroll
        for (int nt = 0; nt < 8; nt++) {
            f32x4 z = (f32x4){0.f, 0.f, 0.f, 0.f};
            s[mt * 8 + nt] = __builtin_amdgcn_mfma_f32_16x16x32_bf16(qf[mt], kf[nt], z, 0, 0, 0);
        }

    float lmax = NEG_INF;
#pragma unroll
    for (int i = 0; i < 16; i++)
        lmax = fmaxf(lmax, fmaxf(fmaxf(s[i][0], s[i][1]), fmaxf(s[i][2], s[i][3])));
    float lsum = 0.f;
#pragma unroll
    for (int i = 0; i < 16; i++)
        lsum += fexp2(s[i][0] - lmax) + fexp2(s[i][1] - lmax) +
                fexp2(s[i][2] - lmax) + fexp2(s[i][3] - lmax);

#pragma unroll
    for (int off = 32; off > 0; off >>= 1) {
        const float omax = __shfl_xor(lmax, off);
        const float osum = __shfl_xor(lsum, off);
        const float nmax = fmaxf(lmax, omax);
        lsum = lsum * fexp2(lmax - nmax) + osum * fexp2(omax - nmax);
        lmax = nmax;
    }
    __shared__ float smax[4], ssum[4];
    if (lane == 0) { smax[w] = lmax; ssum[w] = lsum; }
    __syncthreads();
    if (tid == 0) {
        float M = smax[0], S = ssum[0];
        for (int i = 1; i < 4; i++) {
            const float nmax = fmaxf(M, smax[i]);
            S = S * fexp2(M - nmax) + ssum[i] * fexp2(smax[i] - nmax);
            M = nmax;
        }
        const int idx = (b * 18 + my) * 18 + mx;
        bmax[idx] = M;
        bsum[idx] = S;
    }
}

__global__ __launch_bounds__(256) void k_fin(
    const float* __restrict__ bmax, const float* __restrict__ bsum,
    float* __restrict__ Ms, float* __restrict__ Sinv)
{
    __shared__ float rmax[256], rsum[256];
    const int b = blockIdx.x, tid = threadIdx.x;
    float lmax = NEG_INF, lsum = 0.f;
    for (int i = tid; i < 324; i += 256) {
        const float m = bmax[b * 324 + i], s = bsum[b * 324 + i];
        const float nmax = fmaxf(lmax, m);
        lsum = lsum * fexp2(lmax - nmax) + s * fexp2(m - nmax);
        lmax = nmax;
    }
    rmax[tid] = lmax; rsum[tid] = lsum;
    __syncthreads();
    for (int st = 128; st > 0; st >>= 1) {
        if (tid < st) {
            const float m2 = rmax[tid + st], s2 = rsum[tid + st];
            const float nmax = fmaxf(rmax[tid], m2);
            rsum[tid] = rsum[tid] * fexp2(rmax[tid] - nmax) + s2 * fexp2(m2 - nmax);
            rmax[tid] = nmax;
        }
        __syncthreads();
    }
    if (tid == 0) { Ms[b] = rmax[0]; Sinv[b] = 1.f / rsum[0]; }
}

// feat: block = 128c x 48n, m-chunks of 128 (2 S-tiles per wave -> 6 S-MFMA +
// 24 PV-MFMA per iter, 18 iters), double-buffered Et, ONE soft barrier per iter.
// More independent MFMA work per dependency-chain stage (latency-bound fix);
// s_setprio(1) around the PV cluster (T5).
// XCD-aware flat grid (768 = 96*8): xcd = wg%8 owns batches {2*xcd, 2*xcd+1}.
__global__ __launch_bounds__(256) void k_feat(
    const unsigned short* __restrict__ Kt, const unsigned short* __restrict__ Qt,
    const unsigned short* __restrict__ Vf, const float* __restrict__ Ms,
    const float* __restrict__ Sinv, float* __restrict__ out)
{
    __shared__ __align__(16) unsigned short Et[2][48][136];   // 48 n x 128 m (+8 pad)
    const int tid = threadIdx.x;
    const int w = tid >> 6, lane = tid & 63;
    const int quad = lane >> 4, l16 = lane & 15;
    const int wg = blockIdx.x;
    const int xcd = wg & 7;
    const int slot = wg >> 3;                 // 0..95
    const int b = xcd * 2 + slot / 48;
    const int n0 = (slot % 48) * 48;
    const unsigned short* Kb = Kt + (size_t)b * NN * 32;
    const unsigned short* Qb = Qt + (size_t)b * NN * 32;
    const unsigned short* Vb = Vf + (size_t)b * C * NN;
    const float M = Ms[b], Si = Sinv[b];

    bf16x8 kf[3];
#pragma unroll
    for (int nt = 0; nt < 3; nt++)
        kf[nt] = *(const bf16x8*)&Kb[(size_t)(n0 + nt * 16 + l16) * 32 + quad * 8];

    f32x4 acc[2][3];
#pragma unroll
    for (int i = 0; i < 2; i++)
#pragma unroll
        for (int j = 0; j < 3; j++) acc[i][j] = (f32x4){0.f, 0.f, 0.f, 0.f};

    // prologue: S(chunk 0) -> Et[0]; qc = Q(chunk 1)
    {
        const bf16x8 q00 = *(const bf16x8*)&Qb[(size_t)(w * 32 + l16) * 32 + quad * 8];
        const bf16x8 q01 = *(const bf16x8*)&Qb[(size_t)(w * 32 + 16 + l16) * 32 + quad * 8];
        f32x4 s0[3], s1[3];
#pragma unroll
        for (int nt = 0; nt < 3; nt++) {
            f32x4 z = (f32x4){0.f, 0.f, 0.f, 0.f};
            s0[nt] = __builtin_amdgcn_mfma_f32_16x16x32_bf16(q00, kf[nt], z, 0, 0, 0);
            s1[nt] = __builtin_amdgcn_mfma_f32_16x16x32_bf16(q01, kf[nt], z, 0, 0, 0);
        }
#pragma unroll
        for (int nt = 0; nt < 3; nt++) {
            const unsigned int a0 = pk2bf(fexp2(s0[nt][0] - M), fexp2(s0[nt][1] - M));
            const unsigned int a1 = pk2bf(fexp2(s0[nt][2] - M), fexp2(s0[nt][3] - M));
            *(uint2*)&Et[0][nt * 16 + l16][w * 32 + quad * 4] = make_uint2(a0, a1);
            const unsigned int b0 = pk2bf(fexp2(s1[nt][0] - M), fexp2(s1[nt][1] - M));
            const unsigned int b1 = pk2bf(fexp2(s1[nt][2] - M), fexp2(s1[nt][3] - M));
            *(uint2*)&Et[0][nt * 16 + l16][w * 32 + 16 + quad * 4] = make_uint2(b0, b1);
        }
    }
    bf16x8 qc0 = *(const bf16x8*)&Qb[(size_t)(128 + w * 32 + l16) * 32 + quad * 8];
    bf16x8 qc1 = *(const bf16x8*)&Qb[(size_t)(128 + w * 32 + 16 + l16) * 32 + quad * 8];
    SOFT_BARRIER();

    for (int k = 0; k < 18; ++k) {
        const int cur = k & 1;
        const int m0 = k * 128;
        // prefetch Q(k+2) and load V(k) early (in flight under the S phase)
        const int mq = (k + 2 < 18 ? k + 2 : 0) * 128;
        bf16x8 qn0 = *(const bf16x8*)&Qb[(size_t)(mq + w * 32 + l16) * 32 + quad * 8];
        bf16x8 qn1 = *(const bf16x8*)&Qb[(size_t)(mq + w * 32 + 16 + l16) * 32 + quad * 8];
        bf16x8 vc[2][4];
#pragma unroll
        for (int ct = 0; ct < 2; ct++)
#pragma unroll
            for (int ks = 0; ks < 4; ks++)
                vc[ct][ks] = *(const bf16x8*)&Vb[(size_t)(w * 32 + ct * 16 + l16) * NN + m0 + ks * 32 + quad * 8];

        // S(k+1) + exp2 -> Et[cur^1] (skipped on last iter)
        if (k < 17) {
            f32x4 s0[3], s1[3];
#pragma unroll
            for (int nt = 0; nt < 3; nt++) {
                f32x4 z = (f32x4){0.f, 0.f, 0.f, 0.f};
                s0[nt] = __builtin_amdgcn_mfma_f32_16x16x32_bf16(qc0, kf[nt], z, 0, 0, 0);
                s1[nt] = __builtin_amdgcn_mfma_f32_16x16x32_bf16(qc1, kf[nt], z, 0, 0, 0);
            }
#pragma unroll
            for (int nt = 0; nt < 3; nt++) {
                const unsigned int a0 = pk2bf(fexp2(s0[nt][0] - M), fexp2(s0[nt][1] - M));
                const unsigned int a1 = pk2bf(fexp2(s0[nt][2] - M), fexp2(s0[nt][3] - M));
                *(uint2*)&Et[cur ^ 1][nt * 16 + l16][w * 32 + quad * 4] = make_uint2(a0, a1);
                const unsigned int b0 = pk2bf(fexp2(s1[nt][0] - M), fexp2(s1[nt][1] - M));
                const unsigned int b1 = pk2bf(fexp2(s1[nt][2] - M), fexp2(s1[nt][3] - M));
                *(uint2*)&Et[cur ^ 1][nt * 16 + l16][w * 32 + 16 + quad * 4] = make_uint2(b0, b1);
            }
        }

        // PV(k) from Et[cur]
        __builtin_amdgcn_s_setprio(1);
#pragma unroll
        for (int ks = 0; ks < 4; ks++) {
#pragma unroll
            for (int nt = 0; nt < 3; nt++) {
                const bf16x8 ef = *(const bf16x8*)&Et[cur][nt * 16 + l16][ks * 32 + quad * 8];
                acc[0][nt] = __builtin_amdgcn_mfma_f32_16x16x32_bf16(vc[0][ks], ef, acc[0][nt], 0, 0, 0);
                acc[1][nt] = __builtin_amdgcn_mfma_f32_16x16x32_bf16(vc[1][ks], ef, acc[1][nt], 0, 0, 0);
            }
        }
        __builtin_amdgcn_s_setprio(0);
        SOFT_BARRIER();
        qc0 = qn0;
        qc1 = qn1;
    }

    float* ob = out + (size_t)b * 2 * C * NN + (size_t)C * NN + n0;
#pragma unroll
    for (int ct = 0; ct < 2; ct++)
#pragma unroll
        for (int nt = 0; nt < 3; nt++)
#pragma unroll
            for (int r = 0; r < 4; r++) {
                const int c = w * 32 + ct * 16 + quad * 4 + r;
                ob[(size_t)c * NN + nt * 16 + l16] = acc[ct][nt][r] * Si;
            }
}

extern "C" void kernel_launch(void* const* d_in, const int* in_sizes, int n_in,
                              void* d_out, int out_size, void* d_ws, size_t ws_size,
                              hipStream_t stream)
{
    const float* x_en   = (const float*)d_in[0];
    const float* x_de   = (const float*)d_in[1];
    const float* x_cat  = (const float*)d_in[2];
    const float* w_kq   = (const float*)d_in[3];
    const float* kq_g   = (const float*)d_in[4];
    const float* kq_b   = (const float*)d_in[5];
    const float* kq_m   = (const float*)d_in[6];
    const float* kq_v   = (const float*)d_in[7];
    const float* w_v    = (const float*)d_in[8];
    const float* v_g    = (const float*)d_in[9];
    const float* v_b    = (const float*)d_in[10];
    const float* v_m    = (const float*)d_in[11];
    const float* v_v    = (const float*)d_in[12];
    const float* w_red  = (const float*)d_in[13];
    const float* red_g  = (const float*)d_in[14];
    const float* red_b  = (const float*)d_in[15];
    const float* red_m  = (const float*)d_in[16];
    const float* red_v  = (const float*)d_in[17];

    unsigned short* Kt      = (unsigned short*)d_ws;
    unsigned short* Qt      = Kt + 1179648;
    unsigned short* Vf      = Qt + 1179648;
    unsigned short* wkq_bf  = Vf + 4718592;
    unsigned short* wv_bf   = wkq_bf + 4096;
    unsigned short* wred_bf = wv_bf + 16384;
    float* bmax = (float*)(wred_bf + 32768);
    float* bsum = bmax + 16 * 324;
    float* Ms   = bsum + 16 * 324;
    float* Sinv = Ms + 16;
    float* kq_sh  = Sinv + 16;
    float* v_sh   = kq_sh + 32;
    float* red_sh = v_sh + 128;
    float* out  = (float*)d_out;

    k_wprep<<<208, 256, 0, stream>>>(
        w_kq, kq_g, kq_b, kq_m, kq_v,
        w_v, v_g, v_b, v_m, v_v,
        w_red, red_g, red_b, red_m, red_v,
        wkq_bf, wv_bf, wred_bf, kq_sh, v_sh, red_sh);

    k_kq  <<<dim3(18, 16, 2), 256, 0, stream>>>(x_en, x_de, wkq_bf, kq_sh, Kt, Qt);
    k_redv<<<dim3(48, 16), 256, 0, stream>>>(x_cat, wred_bf, red_sh, wv_bf, v_sh, out, Vf);

    k_stats<<<5184, 256, 0, stream>>>(Kt, Qt, bmax, bsum);
    k_fin  <<<16, 256, 0, stream>>>(bmax, bsum, Ms, Sinv);
    k_feat <<<768, 256, 0, stream>>>(Kt, Qt, Vf, Ms, Sinv, out);
}

// Round 6
// 224.733 us; speedup vs baseline: 1.1089x; 1.1089x over previous
//
#include <hip/hip_runtime.h>
#include <math.h>

#define C    128
#define C4   32
#define NN   2304          // 48*48
#define BN_EPS 1e-5f
#define NEG_INF -3.402823466e38f
#define LOG2E 1.4426950408889634f

typedef short bf16x8 __attribute__((ext_vector_type(8)));
typedef float f32x4 __attribute__((ext_vector_type(4)));

// barrier that only drains LDS (lgkmcnt) — leaves prefetched global loads in flight.
#define SOFT_BARRIER() asm volatile("s_waitcnt lgkmcnt(0)\n\ts_barrier" ::: "memory")

__device__ inline unsigned short f2bf(float f) {
    unsigned int u = __float_as_uint(f);
    u += 0x7fffu + ((u >> 16) & 1u);
    return (unsigned short)(u >> 16);
}

__device__ inline unsigned int pk2bf(float a, float b) {
#if __has_builtin(__builtin_amdgcn_cvt_pk_bf16_f32)
    typedef __bf16 bf2 __attribute__((ext_vector_type(2)));
    bf2 v = __builtin_amdgcn_cvt_pk_bf16_f32(a, b);
    return __builtin_bit_cast(unsigned int, v);
#else
    unsigned int ua = __float_as_uint(a); ua += 0x7fffu + ((ua >> 16) & 1u);
    unsigned int ub = __float_as_uint(b); ub += 0x7fffu + ((ub >> 16) & 1u);
    return __builtin_amdgcn_perm(ub, ua, 0x07060302u);
#endif
}

__device__ inline float fexp2(float x) {
#if __has_builtin(__builtin_amdgcn_exp2f)
    return __builtin_amdgcn_exp2f(x);
#else
    return __expf(x * 0.69314718055994531f);
#endif
}

// ---------------- workspace layout ----------------
// ushort region:
//   Kt  [16][2304][32]      @0         (1179648)   NOTE: K pre-scaled by log2(e)
//   Qt  [16][2304][32]      @1179648   (1179648)
//   Vf  [16][72][128][32]   @2359296   (4718592)   m-TILED: [b][m/32][c][m%32]
//   wkq_bf [32][128]        @7077888   (4096)
//   wv_bf  [128][128]       @7081984   (16384)
//   wred_bf[128][256]       @7098368   (32768)
// float region:
//   bmax[16*324], bsum[16*324], Ms[16], Sinv[16], kq_sh[32], v_sh[128], red_sh[128]

__global__ __launch_bounds__(256) void k_wprep(
    const float* __restrict__ wkq, const float* __restrict__ kq_g,
    const float* __restrict__ kq_b, const float* __restrict__ kq_m,
    const float* __restrict__ kq_v,
    const float* __restrict__ wv, const float* __restrict__ v_g,
    const float* __restrict__ v_b, const float* __restrict__ v_m,
    const float* __restrict__ v_v,
    const float* __restrict__ wred, const float* __restrict__ red_g,
    const float* __restrict__ red_b, const float* __restrict__ red_m,
    const float* __restrict__ red_v,
    unsigned short* __restrict__ wkq_bf, unsigned short* __restrict__ wv_bf,
    unsigned short* __restrict__ wred_bf,
    float* __restrict__ kq_sh, float* __restrict__ v_sh, float* __restrict__ red_sh)
{
    const int t = blockIdx.x * 256 + threadIdx.x;
    if (t < 4096) {
        const int o = t >> 7;
        const float sc = kq_g[o] * rsqrtf(kq_v[o] + BN_EPS);
        wkq_bf[t] = f2bf(wkq[t] * sc);
        if ((t & 127) == 0) kq_sh[o] = kq_b[o] - kq_m[o] * sc;
    } else if (t < 4096 + 16384) {
        const int e = t - 4096;
        const int o = e >> 7;
        const float sc = v_g[o] * rsqrtf(v_v[o] + BN_EPS);
        wv_bf[e] = f2bf(wv[e] * sc);
        if ((e & 127) == 0) v_sh[o] = v_b[o] - v_m[o] * sc;
    } else if (t < 4096 + 16384 + 32768) {
        const int e = t - 20480;
        const int o = e >> 8;
        const float sc = red_g[o] * rsqrtf(red_v[o] + BN_EPS);
        wred_bf[e] = f2bf(wred[e] * sc);
        if ((e & 255) == 0) red_sh[o] = red_b[o] - red_m[o] * sc;
    }
}

// ---- fused producer kernel: blocks 0..767 = red+V conv, blocks 768..1343 = K/Q conv.
// Both paths identical math to the previously-passing k_redv / k_kq; only the
// block decode and a shared LDS overlay differ. Vf written in m-tiled layout.
__global__ __launch_bounds__(256) void k_kqredv(
    const float* __restrict__ x0, const float* __restrict__ x1,
    const float* __restrict__ xcat,
    const unsigned short* __restrict__ wbf, const float* __restrict__ shift,
    unsigned short* __restrict__ Kt, unsigned short* __restrict__ Qt,
    const unsigned short* __restrict__ wred_bf, const float* __restrict__ red_sh,
    const unsigned short* __restrict__ wv_bf,  const float* __restrict__ v_sh,
    float* __restrict__ out, unsigned short* __restrict__ Vf)
{
    __shared__ __align__(16) unsigned char smem[20608];
    const int wg = blockIdx.x;
    const int tid = threadIdx.x;
    const int w = tid >> 6, lane = tid & 63;
    const int quad = lane >> 4, l16 = lane & 15;
    const int p = tid & 15, g = tid >> 4;

    if (wg < 768) {
        // ================= red + V path =================
        typedef unsigned short XsT[48][40];
        XsT* Xs = (XsT*)smem;                            // Xs[2][48][40]  (7680 B)
        unsigned int* Xv = (unsigned int*)(smem + 7680); // Xv[64*49]      (12544 B)

        const int b = wg / 48, n0 = (wg % 48) * 48;
        const float* xin = xcat + (size_t)b * 2 * C * NN;

        f32x4 acc[2][3];
#pragma unroll
        for (int mt = 0; mt < 2; mt++)
#pragma unroll
            for (int nt = 0; nt < 3; nt++) acc[mt][nt] = (f32x4){0.f, 0.f, 0.f, 0.f};

        float4 av, bv;
        if (g < 12) {
            const float* xr = xin + (size_t)(2 * p) * NN + n0 + g * 4;
            av = *(const float4*)&xr[0];
            bv = *(const float4*)&xr[NN];
        }

        for (int k = 0; k < 8; ++k) {
            if (g < 12) {
                const unsigned int u0 = pk2bf(av.x, bv.x);
                const unsigned int u1 = pk2bf(av.y, bv.y);
                const unsigned int u2 = pk2bf(av.z, bv.z);
                const unsigned int u3 = pk2bf(av.w, bv.w);
                if (k < 7) {
                    const float* xr = xin + (size_t)((k + 1) * 32 + 2 * p) * NN + n0 + g * 4;
                    av = *(const float4*)&xr[0];
                    bv = *(const float4*)&xr[NN];
                }
                unsigned int* Xw = (unsigned int*)Xs[k & 1];
                Xw[(g * 4 + 0) * 20 + p] = u0;
                Xw[(g * 4 + 1) * 20 + p] = u1;
                Xw[(g * 4 + 2) * 20 + p] = u2;
                Xw[(g * 4 + 3) * 20 + p] = u3;
            }
            SOFT_BARRIER();
            bf16x8 af[2];
#pragma unroll
            for (int mt = 0; mt < 2; mt++)
                af[mt] = *(const bf16x8*)&wred_bf[(size_t)(w * 32 + mt * 16 + l16) * (2 * C) + k * 32 + quad * 8];
#pragma unroll
            for (int nt = 0; nt < 3; nt++) {
                const bf16x8 bfr = *(const bf16x8*)&Xs[k & 1][nt * 16 + l16][quad * 8];
#pragma unroll
                for (int mt = 0; mt < 2; mt++)
                    acc[mt][nt] = __builtin_amdgcn_mfma_f32_16x16x32_bf16(af[mt], bfr, acc[mt][nt], 0, 0, 0);
            }
        }

        // red epilogue: fp32 -> d_out, bf16 pairs -> Xv[cp][n]
        {
            float* ob = out + (size_t)b * (2 * C * NN);
#pragma unroll
            for (int mt = 0; mt < 2; mt++) {
                float sh[4];
#pragma unroll
                for (int r = 0; r < 4; r++) sh[r] = red_sh[w * 32 + mt * 16 + quad * 4 + r];
#pragma unroll
                for (int nt = 0; nt < 3; nt++) {
                    const int n = n0 + nt * 16 + l16;
                    float v[4];
#pragma unroll
                    for (int r = 0; r < 4; r++) {
                        const int o = w * 32 + mt * 16 + quad * 4 + r;
                        v[r] = fmaxf(acc[mt][nt][r] + sh[r], 0.f);
                        ob[(size_t)o * NN + n] = v[r];
                    }
                    const int op0 = 16 * w + mt * 8 + quad * 2;
                    Xv[(op0 + 0) * 49 + nt * 16 + l16] = pk2bf(v[0], v[1]);
                    Xv[(op0 + 1) * 49 + nt * 16 + l16] = pk2bf(v[2], v[3]);
                }
            }
        }
        SOFT_BARRIER();

        // V phase: 128-c sweep reading x from Xv
        f32x4 vacc[2][3];
#pragma unroll
        for (int mt = 0; mt < 2; mt++)
#pragma unroll
            for (int nt = 0; nt < 3; nt++) vacc[mt][nt] = (f32x4){0.f, 0.f, 0.f, 0.f};

        for (int c0 = 0; c0 < C; c0 += 32) {
            bf16x8 af[2];
#pragma unroll
            for (int mt = 0; mt < 2; mt++)
                af[mt] = *(const bf16x8*)&wv_bf[(size_t)(w * 32 + mt * 16 + l16) * C + c0 + quad * 8];
#pragma unroll
            for (int nt = 0; nt < 3; nt++) {
                const int col = nt * 16 + l16;
                const int cp0 = c0 / 2 + quad * 4;
                uint4 u;
                u.x = Xv[(cp0 + 0) * 49 + col];
                u.y = Xv[(cp0 + 1) * 49 + col];
                u.z = Xv[(cp0 + 2) * 49 + col];
                u.w = Xv[(cp0 + 3) * 49 + col];
                const bf16x8 bfr = __builtin_bit_cast(bf16x8, u);
#pragma unroll
                for (int mt = 0; mt < 2; mt++)
                    vacc[mt][nt] = __builtin_amdgcn_mfma_f32_16x16x32_bf16(af[mt], bfr, vacc[mt][nt], 0, 0, 0);
            }
        }

#pragma unroll
        for (int mt = 0; mt < 2; mt++) {
            float sh[4];
#pragma unroll
            for (int r = 0; r < 4; r++) sh[r] = v_sh[w * 32 + mt * 16 + quad * 4 + r];
#pragma unroll
            for (int nt = 0; nt < 3; nt++)
#pragma unroll
                for (int r = 0; r < 4; r++) {
                    const int o = w * 32 + mt * 16 + quad * 4 + r;
                    const int n = n0 + nt * 16 + l16;
                    // m-tiled Vf: [b][n/32][c][n%32]
                    Vf[(((size_t)b * 72 + (n >> 5)) * 128 + o) * 32 + (n & 31)] =
                        f2bf(fmaxf(vacc[mt][nt][r] + sh[r], 0.f));
                }
        }
    } else {
        // ================= K/Q path =================
        typedef unsigned short Xs2T[128][40];
        Xs2T* Xs = (Xs2T*)smem;                          // Xs[2][128][40] (20480 B)
        constexpr int R = 8;

        const int e = wg - 768;
        const int z = e / 288;
        const int rem = e - z * 288;
        const int b = rem / 18, n0 = (rem % 18) * 128;
        const int nbase = w * 32;

        const float* xin = (z ? x1 : x0) + (size_t)b * C * NN;

        f32x4 acc[2][2];
#pragma unroll
        for (int mt = 0; mt < 2; mt++)
#pragma unroll
            for (int nt = 0; nt < 2; nt++) acc[mt][nt] = (f32x4){0.f, 0.f, 0.f, 0.f};

        const float* xrb = xin + n0 + g * R;
        float av[R], bv[R];
        {
            const float* xr = xrb + (size_t)(2 * p) * NN;
#pragma unroll
            for (int i4 = 0; i4 < R; i4 += 4) {
                *(float4*)&av[i4] = *(const float4*)&xr[i4];
                *(float4*)&bv[i4] = *(const float4*)&xr[NN + i4];
            }
        }

        for (int k = 0; k < 4; ++k) {
            unsigned int uu[R];
#pragma unroll
            for (int i = 0; i < R; i++) uu[i] = pk2bf(av[i], bv[i]);
            if (k < 3) {
                const float* xr = xrb + (size_t)((k + 1) * 32 + 2 * p) * NN;
#pragma unroll
                for (int i4 = 0; i4 < R; i4 += 4) {
                    *(float4*)&av[i4] = *(const float4*)&xr[i4];
                    *(float4*)&bv[i4] = *(const float4*)&xr[NN + i4];
                }
            }
            unsigned int* Xw = (unsigned int*)Xs[k & 1];
#pragma unroll
            for (int i = 0; i < R; i++)
                Xw[(g * R + i) * 20 + p] = uu[i];
            SOFT_BARRIER();
            bf16x8 af[2];
#pragma unroll
            for (int mt = 0; mt < 2; mt++)
                af[mt] = *(const bf16x8*)&wbf[(size_t)(mt * 16 + l16) * C + k * 32 + quad * 8];
#pragma unroll
            for (int nt = 0; nt < 2; nt++) {
                const bf16x8 bfr = *(const bf16x8*)&Xs[k & 1][nbase + nt * 16 + l16][quad * 8];
#pragma unroll
                for (int mt = 0; mt < 2; mt++)
                    acc[mt][nt] = __builtin_amdgcn_mfma_f32_16x16x32_bf16(af[mt], bfr, acc[mt][nt], 0, 0, 0);
            }
        }

        unsigned short* ob16 = z ? Qt : Kt;
        const float osc = z ? 1.f : LOG2E;
#pragma unroll
        for (int mt = 0; mt < 2; mt++)
#pragma unroll
            for (int nt = 0; nt < 2; nt++)
#pragma unroll
                for (int r = 0; r < 4; r++) {
                    const int o = mt * 16 + quad * 4 + r;
                    const int n = n0 + nbase + nt * 16 + l16;
                    const float sh = shift[o];
                    ob16[((size_t)b * NN + n) * 32 + o] =
                        f2bf(fmaxf(acc[mt][nt][r] + sh, 0.f) * osc);
                }
    }
}

// stats: 128(m) x 128(n) scaled-KQ tile; all 16 MFMAs first, then bulk reduce.
// XCD-aware flat grid (5184 = 648*8).
__global__ __launch_bounds__(256) void k_stats(
    const unsigned short* __restrict__ Kt, const unsigned short* __restrict__ Qt,
    float* __restrict__ bmax, float* __restrict__ bsum)
{
    const int tid = threadIdx.x;
    const int w = tid >> 6, lane = tid & 63;
    const int quad = lane >> 4, l16 = lane & 15;
    const int wg = blockIdx.x;
    const int xcd = wg & 7;
    const int slot = wg >> 3;
    const int b = xcd * 2 + slot / 324;
    const int tile = slot % 324;
    const int my = tile / 18, mx = tile % 18;
    const int n0 = mx * 128, m0 = my * 128;
    const unsigned short* Kb = Kt + (size_t)b * NN * 32;
    const unsigned short* Qb = Qt + (size_t)b * NN * 32;

    bf16x8 kf[8], qf[2];
#pragma unroll
    for (int nt = 0; nt < 8; nt++)
        kf[nt] = *(const bf16x8*)&Kb[(size_t)(n0 + nt * 16 + l16) * 32 + quad * 8];
#pragma unroll
    for (int mt = 0; mt < 2; mt++)
        qf[mt] = *(const bf16x8*)&Qb[(size_t)(m0 + w * 32 + mt * 16 + l16) * 32 + quad * 8];

    f32x4 s[16];
#pragma unroll
    for (int mt = 0; mt < 2; mt++)
#pragma unroll
        for (int nt = 0; nt < 8; nt++) {
            f32x4 z = (f32x4){0.f, 0.f, 0.f, 0.f};
            s[mt * 8 + nt] = __builtin_amdgcn_mfma_f32_16x16x32_bf16(qf[mt], kf[nt], z, 0, 0, 0);
        }

    float lmax = NEG_INF;
#pragma unroll
    for (int i = 0; i < 16; i++)
        lmax = fmaxf(lmax, fmaxf(fmaxf(s[i][0], s[i][1]), fmaxf(s[i][2], s[i][3])));
    float lsum = 0.f;
#pragma unroll
    for (int i = 0; i < 16; i++)
        lsum += fexp2(s[i][0] - lmax) + fexp2(s[i][1] - lmax) +
                fexp2(s[i][2] - lmax) + fexp2(s[i][3] - lmax);

#pragma unroll
    for (int off = 32; off > 0; off >>= 1) {
        const float omax = __shfl_xor(lmax, off);
        const float osum = __shfl_xor(lsum, off);
        const float nmax = fmaxf(lmax, omax);
        lsum = lsum * fexp2(lmax - nmax) + osum * fexp2(omax - nmax);
        lmax = nmax;
    }
    __shared__ float smax[4], ssum[4];
    if (lane == 0) { smax[w] = lmax; ssum[w] = lsum; }
    __syncthreads();
    if (tid == 0) {
        float M = smax[0], S = ssum[0];
        for (int i = 1; i < 4; i++) {
            const float nmax = fmaxf(M, smax[i]);
            S = S * fexp2(M - nmax) + ssum[i] * fexp2(smax[i] - nmax);
            M = nmax;
        }
        const int idx = (b * 18 + my) * 18 + mx;
        bmax[idx] = M;
        bsum[idx] = S;
    }
}

__global__ __launch_bounds__(256) void k_fin(
    const float* __restrict__ bmax, const float* __restrict__ bsum,
    float* __restrict__ Ms, float* __restrict__ Sinv)
{
    __shared__ float rmax[256], rsum[256];
    const int b = blockIdx.x, tid = threadIdx.x;
    float lmax = NEG_INF, lsum = 0.f;
    for (int i = tid; i < 324; i += 256) {
        const float m = bmax[b * 324 + i], s = bsum[b * 324 + i];
        const float nmax = fmaxf(lmax, m);
        lsum = lsum * fexp2(lmax - nmax) + s * fexp2(m - nmax);
        lmax = nmax;
    }
    rmax[tid] = lmax; rsum[tid] = lsum;
    __syncthreads();
    for (int st = 128; st > 0; st >>= 1) {
        if (tid < st) {
            const float m2 = rmax[tid + st], s2 = rsum[tid + st];
            const float nmax = fmaxf(rmax[tid], m2);
            rsum[tid] = rsum[tid] * fexp2(rmax[tid] - nmax) + s2 * fexp2(m2 - nmax);
            rmax[tid] = nmax;
        }
        __syncthreads();
    }
    if (tid == 0) { Ms[b] = rmax[0]; Sinv[b] = 1.f / rsum[0]; }
}

// feat: block = 128c x 48n, m-chunks of 128 (18 iters), double-buffered Et,
// one soft barrier per iter, setprio around PV. V read from m-TILED Vf:
// vc load = 16 rows x 64B CONTIGUOUS (1KB dense burst) instead of 16-way
// 4.6KB-strided gather — tests the "V spatial pattern is the rate limiter" theory.
// XCD-aware flat grid (768 = 96*8).
__global__ __launch_bounds__(256) void k_feat(
    const unsigned short* __restrict__ Kt, const unsigned short* __restrict__ Qt,
    const unsigned short* __restrict__ Vf, const float* __restrict__ Ms,
    const float* __restrict__ Sinv, float* __restrict__ out)
{
    __shared__ __align__(16) unsigned short Et[2][48][136];
    const int tid = threadIdx.x;
    const int w = tid >> 6, lane = tid & 63;
    const int quad = lane >> 4, l16 = lane & 15;
    const int wg = blockIdx.x;
    const int xcd = wg & 7;
    const int slot = wg >> 3;
    const int b = xcd * 2 + slot / 48;
    const int n0 = (slot % 48) * 48;
    const unsigned short* Kb = Kt + (size_t)b * NN * 32;
    const unsigned short* Qb = Qt + (size_t)b * NN * 32;
    const unsigned short* Vb = Vf + (size_t)b * 72 * 128 * 32;   // m-tiled base
    const float M = Ms[b], Si = Sinv[b];

    bf16x8 kf[3];
#pragma unroll
    for (int nt = 0; nt < 3; nt++)
        kf[nt] = *(const bf16x8*)&Kb[(size_t)(n0 + nt * 16 + l16) * 32 + quad * 8];

    f32x4 acc[2][3];
#pragma unroll
    for (int i = 0; i < 2; i++)
#pragma unroll
        for (int j = 0; j < 3; j++) acc[i][j] = (f32x4){0.f, 0.f, 0.f, 0.f};

    // prologue: S(chunk 0) -> Et[0]; qc = Q(chunk 1)
    {
        const bf16x8 q00 = *(const bf16x8*)&Qb[(size_t)(w * 32 + l16) * 32 + quad * 8];
        const bf16x8 q01 = *(const bf16x8*)&Qb[(size_t)(w * 32 + 16 + l16) * 32 + quad * 8];
        f32x4 s0[3], s1[3];
#pragma unroll
        for (int nt = 0; nt < 3; nt++) {
            f32x4 z = (f32x4){0.f, 0.f, 0.f, 0.f};
            s0[nt] = __builtin_amdgcn_mfma_f32_16x16x32_bf16(q00, kf[nt], z, 0, 0, 0);
            s1[nt] = __builtin_amdgcn_mfma_f32_16x16x32_bf16(q01, kf[nt], z, 0, 0, 0);
        }
#pragma unroll
        for (int nt = 0; nt < 3; nt++) {
            const unsigned int a0 = pk2bf(fexp2(s0[nt][0] - M), fexp2(s0[nt][1] - M));
            const unsigned int a1 = pk2bf(fexp2(s0[nt][2] - M), fexp2(s0[nt][3] - M));
            *(uint2*)&Et[0][nt * 16 + l16][w * 32 + quad * 4] = make_uint2(a0, a1);
            const unsigned int b0 = pk2bf(fexp2(s1[nt][0] - M), fexp2(s1[nt][1] - M));
            const unsigned int b1 = pk2bf(fexp2(s1[nt][2] - M), fexp2(s1[nt][3] - M));
            *(uint2*)&Et[0][nt * 16 + l16][w * 32 + 16 + quad * 4] = make_uint2(b0, b1);
        }
    }
    bf16x8 qc0 = *(const bf16x8*)&Qb[(size_t)(128 + w * 32 + l16) * 32 + quad * 8];
    bf16x8 qc1 = *(const bf16x8*)&Qb[(size_t)(128 + w * 32 + 16 + l16) * 32 + quad * 8];
    SOFT_BARRIER();

    for (int k = 0; k < 18; ++k) {
        const int cur = k & 1;
        const int mt0 = k * 4;                       // m-tile index (32-wide tiles)
        const int mq = (k + 2 < 18 ? k + 2 : 0) * 128;
        bf16x8 qn0 = *(const bf16x8*)&Qb[(size_t)(mq + w * 32 + l16) * 32 + quad * 8];
        bf16x8 qn1 = *(const bf16x8*)&Qb[(size_t)(mq + w * 32 + 16 + l16) * 32 + quad * 8];
        bf16x8 vc[2][4];
#pragma unroll
        for (int ct = 0; ct < 2; ct++)
#pragma unroll
            for (int ks = 0; ks < 4; ks++)
                vc[ct][ks] = *(const bf16x8*)&Vb[(((size_t)(mt0 + ks)) * 128 + w * 32 + ct * 16 + l16) * 32 + quad * 8];

        if (k < 17) {
            f32x4 s0[3], s1[3];
#pragma unroll
            for (int nt = 0; nt < 3; nt++) {
                f32x4 z = (f32x4){0.f, 0.f, 0.f, 0.f};
                s0[nt] = __builtin_amdgcn_mfma_f32_16x16x32_bf16(qc0, kf[nt], z, 0, 0, 0);
                s1[nt] = __builtin_amdgcn_mfma_f32_16x16x32_bf16(qc1, kf[nt], z, 0, 0, 0);
            }
#pragma unroll
            for (int nt = 0; nt < 3; nt++) {
                const unsigned int a0 = pk2bf(fexp2(s0[nt][0] - M), fexp2(s0[nt][1] - M));
                const unsigned int a1 = pk2bf(fexp2(s0[nt][2] - M), fexp2(s0[nt][3] - M));
                *(uint2*)&Et[cur ^ 1][nt * 16 + l16][w * 32 + quad * 4] = make_uint2(a0, a1);
                const unsigned int b0 = pk2bf(fexp2(s1[nt][0] - M), fexp2(s1[nt][1] - M));
                const unsigned int b1 = pk2bf(fexp2(s1[nt][2] - M), fexp2(s1[nt][3] - M));
                *(uint2*)&Et[cur ^ 1][nt * 16 + l16][w * 32 + 16 + quad * 4] = make_uint2(b0, b1);
            }
        }

        __builtin_amdgcn_s_setprio(1);
#pragma unroll
        for (int ks = 0; ks < 4; ks++) {
#pragma unroll
            for (int nt = 0; nt < 3; nt++) {
                const bf16x8 ef = *(const bf16x8*)&Et[cur][nt * 16 + l16][ks * 32 + quad * 8];
                acc[0][nt] = __builtin_amdgcn_mfma_f32_16x16x32_bf16(vc[0][ks], ef, acc[0][nt], 0, 0, 0);
                acc[1][nt] = __builtin_amdgcn_mfma_f32_16x16x32_bf16(vc[1][ks], ef, acc[1][nt], 0, 0, 0);
            }
        }
        __builtin_amdgcn_s_setprio(0);
        SOFT_BARRIER();
        qc0 = qn0;
        qc1 = qn1;
    }

    float* ob = out + (size_t)b * 2 * C * NN + (size_t)C * NN + n0;
#pragma unroll
    for (int ct = 0; ct < 2; ct++)
#pragma unroll
        for (int nt = 0; nt < 3; nt++)
#pragma unroll
            for (int r = 0; r < 4; r++) {
                const int c = w * 32 + ct * 16 + quad * 4 + r;
                ob[(size_t)c * NN + nt * 16 + l16] = acc[ct][nt][r] * Si;
            }
}

extern "C" void kernel_launch(void* const* d_in, const int* in_sizes, int n_in,
                              void* d_out, int out_size, void* d_ws, size_t ws_size,
                              hipStream_t stream)
{
    const float* x_en   = (const float*)d_in[0];
    const float* x_de   = (const float*)d_in[1];
    const float* x_cat  = (const float*)d_in[2];
    const float* w_kq   = (const float*)d_in[3];
    const float* kq_g   = (const float*)d_in[4];
    const float* kq_b   = (const float*)d_in[5];
    const float* kq_m   = (const float*)d_in[6];
    const float* kq_v   = (const float*)d_in[7];
    const float* w_v    = (const float*)d_in[8];
    const float* v_g    = (const float*)d_in[9];
    const float* v_b    = (const float*)d_in[10];
    const float* v_m    = (const float*)d_in[11];
    const float* v_v    = (const float*)d_in[12];
    const float* w_red  = (const float*)d_in[13];
    const float* red_g  = (const float*)d_in[14];
    const float* red_b  = (const float*)d_in[15];
    const float* red_m  = (const float*)d_in[16];
    const float* red_v  = (const float*)d_in[17];

    unsigned short* Kt      = (unsigned short*)d_ws;
    unsigned short* Qt      = Kt + 1179648;
    unsigned short* Vf      = Qt + 1179648;
    unsigned short* wkq_bf  = Vf + 4718592;
    unsigned short* wv_bf   = wkq_bf + 4096;
    unsigned short* wred_bf = wv_bf + 16384;
    float* bmax = (float*)(wred_bf + 32768);
    float* bsum = bmax + 16 * 324;
    float* Ms   = bsum + 16 * 324;
    float* Sinv = Ms + 16;
    float* kq_sh  = Sinv + 16;
    float* v_sh   = kq_sh + 32;
    float* red_sh = v_sh + 128;
    float* out  = (float*)d_out;

    k_wprep<<<208, 256, 0, stream>>>(
        w_kq, kq_g, kq_b, kq_m, kq_v,
        w_v, v_g, v_b, v_m, v_v,
        w_red, red_g, red_b, red_m, red_v,
        wkq_bf, wv_bf, wred_bf, kq_sh, v_sh, red_sh);

    k_kqredv<<<1344, 256, 0, stream>>>(
        x_en, x_de, x_cat, wkq_bf, kq_sh, Kt, Qt,
        wred_bf, red_sh, wv_bf, v_sh, out, Vf);

    k_stats<<<5184, 256, 0, stream>>>(Kt, Qt, bmax, bsum);
    k_fin  <<<16, 256, 0, stream>>>(bmax, bsum, Ms, Sinv);
    k_feat <<<768, 256, 0, stream>>>(Kt, Qt, Vf, Ms, Sinv, out);
}

// Round 7
// 220.117 us; speedup vs baseline: 1.1321x; 1.0210x over previous
//
#include <hip/hip_runtime.h>
#include <math.h>

#define C    128
#define C4   32
#define NN   2304          // 48*48
#define BN_EPS 1e-5f
#define NEG_INF -3.402823466e38f
#define LOG2E 1.4426950408889634f

typedef short bf16x8 __attribute__((ext_vector_type(8)));
typedef float f32x4 __attribute__((ext_vector_type(4)));

// barrier that only drains LDS (lgkmcnt) — leaves prefetched global loads in flight.
#define SOFT_BARRIER() asm volatile("s_waitcnt lgkmcnt(0)\n\ts_barrier" ::: "memory")

__device__ inline unsigned short f2bf(float f) {
    unsigned int u = __float_as_uint(f);
    u += 0x7fffu + ((u >> 16) & 1u);
    return (unsigned short)(u >> 16);
}

__device__ inline unsigned int pk2bf(float a, float b) {
#if __has_builtin(__builtin_amdgcn_cvt_pk_bf16_f32)
    typedef __bf16 bf2 __attribute__((ext_vector_type(2)));
    bf2 v = __builtin_amdgcn_cvt_pk_bf16_f32(a, b);
    return __builtin_bit_cast(unsigned int, v);
#else
    unsigned int ua = __float_as_uint(a); ua += 0x7fffu + ((ua >> 16) & 1u);
    unsigned int ub = __float_as_uint(b); ub += 0x7fffu + ((ub >> 16) & 1u);
    return __builtin_amdgcn_perm(ub, ua, 0x07060302u);
#endif
}

__device__ inline float fexp2(float x) {
#if __has_builtin(__builtin_amdgcn_exp2f)
    return __builtin_amdgcn_exp2f(x);
#else
    return __expf(x * 0.69314718055994531f);
#endif
}

// ---------------- workspace layout ----------------
// ushort region:
//   Kt  [16][2304][32]      @0         (1179648)   NOTE: K pre-scaled by log2(e)
//   Qt  [16][2304][32]      @1179648   (1179648)
//   Vf  [16][72][128][32]   @2359296   (4718592)   m-TILED: [b][m/32][c][m%32]
//   wkq_bf [32][128]        @7077888   (4096)
//   wv_bf  [128][128]       @7081984   (16384)
//   wred_bf[128][256]       @7098368   (32768)
// float region:
//   bmax[16*324], bsum[16*324], Ms[16], Sinv[16], kq_sh[32], v_sh[128], red_sh[128]

__global__ __launch_bounds__(256) void k_wprep(
    const float* __restrict__ wkq, const float* __restrict__ kq_g,
    const float* __restrict__ kq_b, const float* __restrict__ kq_m,
    const float* __restrict__ kq_v,
    const float* __restrict__ wv, const float* __restrict__ v_g,
    const float* __restrict__ v_b, const float* __restrict__ v_m,
    const float* __restrict__ v_v,
    const float* __restrict__ wred, const float* __restrict__ red_g,
    const float* __restrict__ red_b, const float* __restrict__ red_m,
    const float* __restrict__ red_v,
    unsigned short* __restrict__ wkq_bf, unsigned short* __restrict__ wv_bf,
    unsigned short* __restrict__ wred_bf,
    float* __restrict__ kq_sh, float* __restrict__ v_sh, float* __restrict__ red_sh)
{
    const int t = blockIdx.x * 256 + threadIdx.x;
    if (t < 4096) {
        const int o = t >> 7;
        const float sc = kq_g[o] * rsqrtf(kq_v[o] + BN_EPS);
        wkq_bf[t] = f2bf(wkq[t] * sc);
        if ((t & 127) == 0) kq_sh[o] = kq_b[o] - kq_m[o] * sc;
    } else if (t < 4096 + 16384) {
        const int e = t - 4096;
        const int o = e >> 7;
        const float sc = v_g[o] * rsqrtf(v_v[o] + BN_EPS);
        wv_bf[e] = f2bf(wv[e] * sc);
        if ((e & 127) == 0) v_sh[o] = v_b[o] - v_m[o] * sc;
    } else if (t < 4096 + 16384 + 32768) {
        const int e = t - 20480;
        const int o = e >> 8;
        const float sc = red_g[o] * rsqrtf(red_v[o] + BN_EPS);
        wred_bf[e] = f2bf(wred[e] * sc);
        if ((e & 255) == 0) red_sh[o] = red_b[o] - red_m[o] * sc;
    }
}

// ---- fused producer kernel: blocks 0..767 = red+V conv, blocks 768..1343 = K/Q conv.
// Staging reads COALESCED: cp = tid>>4 (channel pair), g = tid&15 (column lane),
// dword loads at column stride 16 -> each 16-lane group reads 64B contiguous.
// LDS layout/content identical to previous rounds (row = n_local, dword col = pair).
__global__ __launch_bounds__(256) void k_kqredv(
    const float* __restrict__ x0, const float* __restrict__ x1,
    const float* __restrict__ xcat,
    const unsigned short* __restrict__ wbf, const float* __restrict__ shift,
    unsigned short* __restrict__ Kt, unsigned short* __restrict__ Qt,
    const unsigned short* __restrict__ wred_bf, const float* __restrict__ red_sh,
    const unsigned short* __restrict__ wv_bf,  const float* __restrict__ v_sh,
    float* __restrict__ out, unsigned short* __restrict__ Vf)
{
    __shared__ __align__(16) unsigned char smem[20608];
    const int wg = blockIdx.x;
    const int tid = threadIdx.x;
    const int w = tid >> 6, lane = tid & 63;
    const int quad = lane >> 4, l16 = lane & 15;
    const int cp = tid >> 4;     // channel pair 0..15
    const int g  = tid & 15;     // column lane 0..15

    if (wg < 768) {
        // ================= red + V path =================
        typedef unsigned short XsT[48][40];
        XsT* Xs = (XsT*)smem;                            // Xs[2][48][40]  (7680 B)
        unsigned int* Xv = (unsigned int*)(smem + 7680); // Xv[64*49]      (12544 B)

        const int b = wg / 48, n0 = (wg % 48) * 48;
        const float* xin = xcat + (size_t)b * 2 * C * NN;

        f32x4 acc[2][3];
#pragma unroll
        for (int mt = 0; mt < 2; mt++)
#pragma unroll
            for (int nt = 0; nt < 3; nt++) acc[mt][nt] = (f32x4){0.f, 0.f, 0.f, 0.f};

        float av[3], bv[3];
        {
            const float* xr = xin + (size_t)(2 * cp) * NN + n0 + g;
#pragma unroll
            for (int j = 0; j < 3; j++) { av[j] = xr[j * 16]; bv[j] = xr[NN + j * 16]; }
        }

        for (int k = 0; k < 8; ++k) {
            unsigned int uu[3];
#pragma unroll
            for (int j = 0; j < 3; j++) uu[j] = pk2bf(av[j], bv[j]);
            if (k < 7) {
                const float* xr = xin + (size_t)((k + 1) * 32 + 2 * cp) * NN + n0 + g;
#pragma unroll
                for (int j = 0; j < 3; j++) { av[j] = xr[j * 16]; bv[j] = xr[NN + j * 16]; }
            }
            unsigned int* Xw = (unsigned int*)Xs[k & 1];
#pragma unroll
            for (int j = 0; j < 3; j++)
                Xw[(j * 16 + g) * 20 + cp] = uu[j];
            SOFT_BARRIER();
            bf16x8 af[2];
#pragma unroll
            for (int mt = 0; mt < 2; mt++)
                af[mt] = *(const bf16x8*)&wred_bf[(size_t)(w * 32 + mt * 16 + l16) * (2 * C) + k * 32 + quad * 8];
#pragma unroll
            for (int nt = 0; nt < 3; nt++) {
                const bf16x8 bfr = *(const bf16x8*)&Xs[k & 1][nt * 16 + l16][quad * 8];
#pragma unroll
                for (int mt = 0; mt < 2; mt++)
                    acc[mt][nt] = __builtin_amdgcn_mfma_f32_16x16x32_bf16(af[mt], bfr, acc[mt][nt], 0, 0, 0);
            }
        }

        // red epilogue: fp32 -> d_out, bf16 pairs -> Xv[cp][n]
        {
            float* ob = out + (size_t)b * (2 * C * NN);
#pragma unroll
            for (int mt = 0; mt < 2; mt++) {
                float sh[4];
#pragma unroll
                for (int r = 0; r < 4; r++) sh[r] = red_sh[w * 32 + mt * 16 + quad * 4 + r];
#pragma unroll
                for (int nt = 0; nt < 3; nt++) {
                    const int n = n0 + nt * 16 + l16;
                    float v[4];
#pragma unroll
                    for (int r = 0; r < 4; r++) {
                        const int o = w * 32 + mt * 16 + quad * 4 + r;
                        v[r] = fmaxf(acc[mt][nt][r] + sh[r], 0.f);
                        ob[(size_t)o * NN + n] = v[r];
                    }
                    const int op0 = 16 * w + mt * 8 + quad * 2;
                    Xv[(op0 + 0) * 49 + nt * 16 + l16] = pk2bf(v[0], v[1]);
                    Xv[(op0 + 1) * 49 + nt * 16 + l16] = pk2bf(v[2], v[3]);
                }
            }
        }
        SOFT_BARRIER();

        // V phase: 128-c sweep reading x from Xv
        f32x4 vacc[2][3];
#pragma unroll
        for (int mt = 0; mt < 2; mt++)
#pragma unroll
            for (int nt = 0; nt < 3; nt++) vacc[mt][nt] = (f32x4){0.f, 0.f, 0.f, 0.f};

        for (int c0 = 0; c0 < C; c0 += 32) {
            bf16x8 af[2];
#pragma unroll
            for (int mt = 0; mt < 2; mt++)
                af[mt] = *(const bf16x8*)&wv_bf[(size_t)(w * 32 + mt * 16 + l16) * C + c0 + quad * 8];
#pragma unroll
            for (int nt = 0; nt < 3; nt++) {
                const int col = nt * 16 + l16;
                const int cp0 = c0 / 2 + quad * 4;
                uint4 u;
                u.x = Xv[(cp0 + 0) * 49 + col];
                u.y = Xv[(cp0 + 1) * 49 + col];
                u.z = Xv[(cp0 + 2) * 49 + col];
                u.w = Xv[(cp0 + 3) * 49 + col];
                const bf16x8 bfr = __builtin_bit_cast(bf16x8, u);
#pragma unroll
                for (int mt = 0; mt < 2; mt++)
                    vacc[mt][nt] = __builtin_amdgcn_mfma_f32_16x16x32_bf16(af[mt], bfr, vacc[mt][nt], 0, 0, 0);
            }
        }

#pragma unroll
        for (int mt = 0; mt < 2; mt++) {
            float sh[4];
#pragma unroll
            for (int r = 0; r < 4; r++) sh[r] = v_sh[w * 32 + mt * 16 + quad * 4 + r];
#pragma unroll
            for (int nt = 0; nt < 3; nt++)
#pragma unroll
                for (int r = 0; r < 4; r++) {
                    const int o = w * 32 + mt * 16 + quad * 4 + r;
                    const int n = n0 + nt * 16 + l16;
                    // m-tiled Vf: [b][n/32][c][n%32]
                    Vf[(((size_t)b * 72 + (n >> 5)) * 128 + o) * 32 + (n & 31)] =
                        f2bf(fmaxf(vacc[mt][nt][r] + sh[r], 0.f));
                }
        }
    } else {
        // ================= K/Q path =================
        typedef unsigned short Xs2T[128][40];
        Xs2T* Xs = (Xs2T*)smem;                          // Xs[2][128][40] (20480 B)

        const int e = wg - 768;
        const int z = e / 288;
        const int rem = e - z * 288;
        const int b = rem / 18, n0 = (rem % 18) * 128;
        const int nbase = w * 32;

        const float* xin = (z ? x1 : x0) + (size_t)b * C * NN;

        f32x4 acc[2][2];
#pragma unroll
        for (int mt = 0; mt < 2; mt++)
#pragma unroll
            for (int nt = 0; nt < 2; nt++) acc[mt][nt] = (f32x4){0.f, 0.f, 0.f, 0.f};

        float av[8], bv[8];
        {
            const float* xr = xin + (size_t)(2 * cp) * NN + n0 + g;
#pragma unroll
            for (int j = 0; j < 8; j++) { av[j] = xr[j * 16]; bv[j] = xr[NN + j * 16]; }
        }

        for (int k = 0; k < 4; ++k) {
            unsigned int uu[8];
#pragma unroll
            for (int j = 0; j < 8; j++) uu[j] = pk2bf(av[j], bv[j]);
            if (k < 3) {
                const float* xr = xin + (size_t)((k + 1) * 32 + 2 * cp) * NN + n0 + g;
#pragma unroll
                for (int j = 0; j < 8; j++) { av[j] = xr[j * 16]; bv[j] = xr[NN + j * 16]; }
            }
            unsigned int* Xw = (unsigned int*)Xs[k & 1];
#pragma unroll
            for (int j = 0; j < 8; j++)
                Xw[(j * 16 + g) * 20 + cp] = uu[j];
            SOFT_BARRIER();
            bf16x8 af[2];
#pragma unroll
            for (int mt = 0; mt < 2; mt++)
                af[mt] = *(const bf16x8*)&wbf[(size_t)(mt * 16 + l16) * C + k * 32 + quad * 8];
#pragma unroll
            for (int nt = 0; nt < 2; nt++) {
                const bf16x8 bfr = *(const bf16x8*)&Xs[k & 1][nbase + nt * 16 + l16][quad * 8];
#pragma unroll
                for (int mt = 0; mt < 2; mt++)
                    acc[mt][nt] = __builtin_amdgcn_mfma_f32_16x16x32_bf16(af[mt], bfr, acc[mt][nt], 0, 0, 0);
            }
        }

        unsigned short* ob16 = z ? Qt : Kt;
        const float osc = z ? 1.f : LOG2E;
#pragma unroll
        for (int mt = 0; mt < 2; mt++)
#pragma unroll
            for (int nt = 0; nt < 2; nt++)
#pragma unroll
                for (int r = 0; r < 4; r++) {
                    const int o = mt * 16 + quad * 4 + r;
                    const int n = n0 + nbase + nt * 16 + l16;
                    const float sh = shift[o];
                    ob16[((size_t)b * NN + n) * 32 + o] =
                        f2bf(fmaxf(acc[mt][nt][r] + sh, 0.f) * osc);
                }
    }
}

// stats: 128(m) x 128(n) scaled-KQ tile; all 16 MFMAs first, then bulk reduce.
// XCD-aware flat grid (5184 = 648*8).
__global__ __launch_bounds__(256) void k_stats(
    const unsigned short* __restrict__ Kt, const unsigned short* __restrict__ Qt,
    float* __restrict__ bmax, float* __restrict__ bsum)
{
    const int tid = threadIdx.x;
    const int w = tid >> 6, lane = tid & 63;
    const int quad = lane >> 4, l16 = lane & 15;
    const int wg = blockIdx.x;
    const int xcd = wg & 7;
    const int slot = wg >> 3;
    const int b = xcd * 2 + slot / 324;
    const int tile = slot % 324;
    const int my = tile / 18, mx = tile % 18;
    const int n0 = mx * 128, m0 = my * 128;
    const unsigned short* Kb = Kt + (size_t)b * NN * 32;
    const unsigned short* Qb = Qt + (size_t)b * NN * 32;

    bf16x8 kf[8], qf[2];
#pragma unroll
    for (int nt = 0; nt < 8; nt++)
        kf[nt] = *(const bf16x8*)&Kb[(size_t)(n0 + nt * 16 + l16) * 32 + quad * 8];
#pragma unroll
    for (int mt = 0; mt < 2; mt++)
        qf[mt] = *(const bf16x8*)&Qb[(size_t)(m0 + w * 32 + mt * 16 + l16) * 32 + quad * 8];

    f32x4 s[16];
#pragma unroll
    for (int mt = 0; mt < 2; mt++)
#pragma unroll
        for (int nt = 0; nt < 8; nt++) {
            f32x4 z = (f32x4){0.f, 0.f, 0.f, 0.f};
            s[mt * 8 + nt] = __builtin_amdgcn_mfma_f32_16x16x32_bf16(qf[mt], kf[nt], z, 0, 0, 0);
        }

    float lmax = NEG_INF;
#pragma unroll
    for (int i = 0; i < 16; i++)
        lmax = fmaxf(lmax, fmaxf(fmaxf(s[i][0], s[i][1]), fmaxf(s[i][2], s[i][3])));
    float lsum = 0.f;
#pragma unroll
    for (int i = 0; i < 16; i++)
        lsum += fexp2(s[i][0] - lmax) + fexp2(s[i][1] - lmax) +
                fexp2(s[i][2] - lmax) + fexp2(s[i][3] - lmax);

#pragma unroll
    for (int off = 32; off > 0; off >>= 1) {
        const float omax = __shfl_xor(lmax, off);
        const float osum = __shfl_xor(lsum, off);
        const float nmax = fmaxf(lmax, omax);
        lsum = lsum * fexp2(lmax - nmax) + osum * fexp2(omax - nmax);
        lmax = nmax;
    }
    __shared__ float smax[4], ssum[4];
    if (lane == 0) { smax[w] = lmax; ssum[w] = lsum; }
    __syncthreads();
    if (tid == 0) {
        float M = smax[0], S = ssum[0];
        for (int i = 1; i < 4; i++) {
            const float nmax = fmaxf(M, smax[i]);
            S = S * fexp2(M - nmax) + ssum[i] * fexp2(smax[i] - nmax);
            M = nmax;
        }
        const int idx = (b * 18 + my) * 18 + mx;
        bmax[idx] = M;
        bsum[idx] = S;
    }
}

__global__ __launch_bounds__(256) void k_fin(
    const float* __restrict__ bmax, const float* __restrict__ bsum,
    float* __restrict__ Ms, float* __restrict__ Sinv)
{
    __shared__ float rmax[256], rsum[256];
    const int b = blockIdx.x, tid = threadIdx.x;
    float lmax = NEG_INF, lsum = 0.f;
    for (int i = tid; i < 324; i += 256) {
        const float m = bmax[b * 324 + i], s = bsum[b * 324 + i];
        const float nmax = fmaxf(lmax, m);
        lsum = lsum * fexp2(lmax - nmax) + s * fexp2(m - nmax);
        lmax = nmax;
    }
    rmax[tid] = lmax; rsum[tid] = lsum;
    __syncthreads();
    for (int st = 128; st > 0; st >>= 1) {
        if (tid < st) {
            const float m2 = rmax[tid + st], s2 = rsum[tid + st];
            const float nmax = fmaxf(rmax[tid], m2);
            rsum[tid] = rsum[tid] * fexp2(rmax[tid] - nmax) + s2 * fexp2(m2 - nmax);
            rmax[tid] = nmax;
        }
        __syncthreads();
    }
    if (tid == 0) { Ms[b] = rmax[0]; Sinv[b] = 1.f / rsum[0]; }
}

// feat: block = 128c x 48n, m-chunks of 128 (18 iters), double-buffered Et,
// one soft barrier per iter, setprio around PV, m-TILED Vf (dense 1KB V bursts).
// XCD-aware flat grid (768 = 96*8).
__global__ __launch_bounds__(256) void k_feat(
    const unsigned short* __restrict__ Kt, const unsigned short* __restrict__ Qt,
    const unsigned short* __restrict__ Vf, const float* __restrict__ Ms,
    const float* __restrict__ Sinv, float* __restrict__ out)
{
    __shared__ __align__(16) unsigned short Et[2][48][136];
    const int tid = threadIdx.x;
    const int w = tid >> 6, lane = tid & 63;
    const int quad = lane >> 4, l16 = lane & 15;
    const int wg = blockIdx.x;
    const int xcd = wg & 7;
    const int slot = wg >> 3;
    const int b = xcd * 2 + slot / 48;
    const int n0 = (slot % 48) * 48;
    const unsigned short* Kb = Kt + (size_t)b * NN * 32;
    const unsigned short* Qb = Qt + (size_t)b * NN * 32;
    const unsigned short* Vb = Vf + (size_t)b * 72 * 128 * 32;   // m-tiled base
    const float M = Ms[b], Si = Sinv[b];

    bf16x8 kf[3];
#pragma unroll
    for (int nt = 0; nt < 3; nt++)
        kf[nt] = *(const bf16x8*)&Kb[(size_t)(n0 + nt * 16 + l16) * 32 + quad * 8];

    f32x4 acc[2][3];
#pragma unroll
    for (int i = 0; i < 2; i++)
#pragma unroll
        for (int j = 0; j < 3; j++) acc[i][j] = (f32x4){0.f, 0.f, 0.f, 0.f};

    // prologue: S(chunk 0) -> Et[0]; qc = Q(chunk 1)
    {
        const bf16x8 q00 = *(const bf16x8*)&Qb[(size_t)(w * 32 + l16) * 32 + quad * 8];
        const bf16x8 q01 = *(const bf16x8*)&Qb[(size_t)(w * 32 + 16 + l16) * 32 + quad * 8];
        f32x4 s0[3], s1[3];
#pragma unroll
        for (int nt = 0; nt < 3; nt++) {
            f32x4 z = (f32x4){0.f, 0.f, 0.f, 0.f};
            s0[nt] = __builtin_amdgcn_mfma_f32_16x16x32_bf16(q00, kf[nt], z, 0, 0, 0);
            s1[nt] = __builtin_amdgcn_mfma_f32_16x16x32_bf16(q01, kf[nt], z, 0, 0, 0);
        }
#pragma unroll
        for (int nt = 0; nt < 3; nt++) {
            const unsigned int a0 = pk2bf(fexp2(s0[nt][0] - M), fexp2(s0[nt][1] - M));
            const unsigned int a1 = pk2bf(fexp2(s0[nt][2] - M), fexp2(s0[nt][3] - M));
            *(uint2*)&Et[0][nt * 16 + l16][w * 32 + quad * 4] = make_uint2(a0, a1);
            const unsigned int b0 = pk2bf(fexp2(s1[nt][0] - M), fexp2(s1[nt][1] - M));
            const unsigned int b1 = pk2bf(fexp2(s1[nt][2] - M), fexp2(s1[nt][3] - M));
            *(uint2*)&Et[0][nt * 16 + l16][w * 32 + 16 + quad * 4] = make_uint2(b0, b1);
        }
    }
    bf16x8 qc0 = *(const bf16x8*)&Qb[(size_t)(128 + w * 32 + l16) * 32 + quad * 8];
    bf16x8 qc1 = *(const bf16x8*)&Qb[(size_t)(128 + w * 32 + 16 + l16) * 32 + quad * 8];
    SOFT_BARRIER();

    for (int k = 0; k < 18; ++k) {
        const int cur = k & 1;
        const int mt0 = k * 4;                       // m-tile index (32-wide tiles)
        const int mq = (k + 2 < 18 ? k + 2 : 0) * 128;
        bf16x8 qn0 = *(const bf16x8*)&Qb[(size_t)(mq + w * 32 + l16) * 32 + quad * 8];
        bf16x8 qn1 = *(const bf16x8*)&Qb[(size_t)(mq + w * 32 + 16 + l16) * 32 + quad * 8];
        bf16x8 vc[2][4];
#pragma unroll
        for (int ct = 0; ct < 2; ct++)
#pragma unroll
            for (int ks = 0; ks < 4; ks++)
                vc[ct][ks] = *(const bf16x8*)&Vb[(((size_t)(mt0 + ks)) * 128 + w * 32 + ct * 16 + l16) * 32 + quad * 8];

        if (k < 17) {
            f32x4 s0[3], s1[3];
#pragma unroll
            for (int nt = 0; nt < 3; nt++) {
                f32x4 z = (f32x4){0.f, 0.f, 0.f, 0.f};
                s0[nt] = __builtin_amdgcn_mfma_f32_16x16x32_bf16(qc0, kf[nt], z, 0, 0, 0);
                s1[nt] = __builtin_amdgcn_mfma_f32_16x16x32_bf16(qc1, kf[nt], z, 0, 0, 0);
            }
#pragma unroll
            for (int nt = 0; nt < 3; nt++) {
                const unsigned int a0 = pk2bf(fexp2(s0[nt][0] - M), fexp2(s0[nt][1] - M));
                const unsigned int a1 = pk2bf(fexp2(s0[nt][2] - M), fexp2(s0[nt][3] - M));
                *(uint2*)&Et[cur ^ 1][nt * 16 + l16][w * 32 + quad * 4] = make_uint2(a0, a1);
                const unsigned int b0 = pk2bf(fexp2(s1[nt][0] - M), fexp2(s1[nt][1] - M));
                const unsigned int b1 = pk2bf(fexp2(s1[nt][2] - M), fexp2(s1[nt][3] - M));
                *(uint2*)&Et[cur ^ 1][nt * 16 + l16][w * 32 + 16 + quad * 4] = make_uint2(b0, b1);
            }
        }

        __builtin_amdgcn_s_setprio(1);
#pragma unroll
        for (int ks = 0; ks < 4; ks++) {
#pragma unroll
            for (int nt = 0; nt < 3; nt++) {
                const bf16x8 ef = *(const bf16x8*)&Et[cur][nt * 16 + l16][ks * 32 + quad * 8];
                acc[0][nt] = __builtin_amdgcn_mfma_f32_16x16x32_bf16(vc[0][ks], ef, acc[0][nt], 0, 0, 0);
                acc[1][nt] = __builtin_amdgcn_mfma_f32_16x16x32_bf16(vc[1][ks], ef, acc[1][nt], 0, 0, 0);
            }
        }
        __builtin_amdgcn_s_setprio(0);
        SOFT_BARRIER();
        qc0 = qn0;
        qc1 = qn1;
    }

    float* ob = out + (size_t)b * 2 * C * NN + (size_t)C * NN + n0;
#pragma unroll
    for (int ct = 0; ct < 2; ct++)
#pragma unroll
        for (int nt = 0; nt < 3; nt++)
#pragma unroll
            for (int r = 0; r < 4; r++) {
                const int c = w * 32 + ct * 16 + quad * 4 + r;
                ob[(size_t)c * NN + nt * 16 + l16] = acc[ct][nt][r] * Si;
            }
}

extern "C" void kernel_launch(void* const* d_in, const int* in_sizes, int n_in,
                              void* d_out, int out_size, void* d_ws, size_t ws_size,
                              hipStream_t stream)
{
    const float* x_en   = (const float*)d_in[0];
    const float* x_de   = (const float*)d_in[1];
    const float* x_cat  = (const float*)d_in[2];
    const float* w_kq   = (const float*)d_in[3];
    const float* kq_g   = (const float*)d_in[4];
    const float* kq_b   = (const float*)d_in[5];
    const float* kq_m   = (const float*)d_in[6];
    const float* kq_v   = (const float*)d_in[7];
    const float* w_v    = (const float*)d_in[8];
    const float* v_g    = (const float*)d_in[9];
    const float* v_b    = (const float*)d_in[10];
    const float* v_m    = (const float*)d_in[11];
    const float* v_v    = (const float*)d_in[12];
    const float* w_red  = (const float*)d_in[13];
    const float* red_g  = (const float*)d_in[14];
    const float* red_b  = (const float*)d_in[15];
    const float* red_m  = (const float*)d_in[16];
    const float* red_v  = (const float*)d_in[17];

    unsigned short* Kt      = (unsigned short*)d_ws;
    unsigned short* Qt      = Kt + 1179648;
    unsigned short* Vf      = Qt + 1179648;
    unsigned short* wkq_bf  = Vf + 4718592;
    unsigned short* wv_bf   = wkq_bf + 4096;
    unsigned short* wred_bf = wv_bf + 16384;
    float* bmax = (float*)(wred_bf + 32768);
    float* bsum = bmax + 16 * 324;
    float* Ms   = bsum + 16 * 324;
    float* Sinv = Ms + 16;
    float* kq_sh  = Sinv + 16;
    float* v_sh   = kq_sh + 32;
    float* red_sh = v_sh + 128;
    float* out  = (float*)d_out;

    k_wprep<<<208, 256, 0, stream>>>(
        w_kq, kq_g, kq_b, kq_m, kq_v,
        w_v, v_g, v_b, v_m, v_v,
        w_red, red_g, red_b, red_m, red_v,
        wkq_bf, wv_bf, wred_bf, kq_sh, v_sh, red_sh);

    k_kqredv<<<1344, 256, 0, stream>>>(
        x_en, x_de, x_cat, wkq_bf, kq_sh, Kt, Qt,
        wred_bf, red_sh, wv_bf, v_sh, out, Vf);

    k_stats<<<5184, 256, 0, stream>>>(Kt, Qt, bmax, bsum);
    k_fin  <<<16, 256, 0, stream>>>(bmax, bsum, Ms, Sinv);
    k_feat <<<768, 256, 0, stream>>>(Kt, Qt, Vf, Ms, Sinv, out);
}